// Round 1
// baseline (618.445 us; speedup 1.0000x reference)
//
#include <hip/hip_runtime.h>

// Shapes fixed by the problem: B=1, H=32, L=8192, S=16384, D=128, g=4.
// Reference reduces to: out_k[h,i,:] = k_val[h,keep[i],:] where
// keep[i] = i (i<4) else i + (S-L); same for V; pos[i] = 1e9 for i<4 else i+(S-L).
// fill_idx == arange(L) always because top_k takes ALL L indices then sorts.

#define HH 32
#define LL 8192
#define SS 16384
#define DD 128
#define GG 4
#define ROW4 (DD / 4)              // 32 float4 per row
#define PER_T (HH * LL * ROW4)     // 8,388,608 float4 per output tensor

__global__ __launch_bounds__(256) void gather_kv_kernel(
    const float4* __restrict__ k_val, const float4* __restrict__ v_val,
    float4* __restrict__ out_k, float4* __restrict__ out_v)
{
    const float4* __restrict__ src = blockIdx.y ? v_val : k_val;
    float4* __restrict__ dst       = blockIdx.y ? out_v : out_k;

    int t = blockIdx.x * blockDim.x + threadIdx.x;   // [0, PER_T)
    // decompose: t = ((h * LL) + i) * ROW4 + c   with LL*ROW4 = 2^18, ROW4 = 2^5
    int h   = t >> 18;
    int rem = t & ((LL * ROW4) - 1);
    int i   = rem >> 5;
    int c   = t & (ROW4 - 1);

    int src_row = (i < GG) ? i : i + (SS - LL);
    // src offset = (h*SS + src_row)*ROW4 + c ; h*SS = h<<14
    int src_off = (((h << 14) + src_row) << 5) | c;

    dst[t] = src[src_off];
}

__global__ __launch_bounds__(256) void pos_kernel(
    const int* __restrict__ input_pos, float* __restrict__ out_pos)
{
    int i = blockIdx.x * blockDim.x + threadIdx.x;
    if (i < LL) {
        int keep_i = (i < GG) ? i : i + (SS - LL);
        int p = input_pos[keep_i];
        float v = (p >= 0 && p < GG) ? 1000000000.0f : (float)p;
        out_pos[i] = v;
    }
}

extern "C" void kernel_launch(void* const* d_in, const int* in_sizes, int n_in,
                              void* d_out, int out_size, void* d_ws, size_t ws_size,
                              hipStream_t stream) {
    // inputs: 0 k_cache, 1 v_cache, 2 k_val, 3 v_val, 4 pos, 5 input_pos
    const float4* k_val = (const float4*)d_in[2];
    const float4* v_val = (const float4*)d_in[3];
    const int* input_pos = (const int*)d_in[5];

    float4* out_k = (float4*)d_out;
    float4* out_v = out_k + PER_T;
    float*  out_p = (float*)d_out + (size_t)2 * HH * LL * DD;

    dim3 grid(PER_T / 256, 2);
    gather_kv_kernel<<<grid, 256, 0, stream>>>(k_val, v_val, out_k, out_v);
    pos_kernel<<<LL / 256, 256, 0, stream>>>(input_pos, out_p);
}